// Round 13
// baseline (338.021 us; speedup 1.0000x reference)
//
#include <hip/hip_runtime.h>

// B=32, N=36, D=2048, C=4, H=512.
// Out[b,i,d] = max_j [ sum_k Wfout[k,d]*(fl[i,k]*fr[j,k])
//                    + sum_ab Mc[ab,d]*(coords[i,a]*coords[j,b]) ] + mm[b,i,d]
// v3: coord branch collapsed via Mc[ab,d]; K: 1024 -> 544 = 17 kc-chunks.
// v5: XCD-clustered grid map + k_mc folded into k_prep.
// v9: counted-vmcnt ring (k_pairwise 121us; staging drain was only ~6%).
// v10: k_prod DELETED — pair products fused into k_pairwise:
//   - per body, each wave computes its granule (t=w) for chunk c+1 from
//     L2-resident bf16 Fl/Fr: 2x16B transient loads -> 8 mul/pack -> 1
//     ds_write_b128 into the other dbuf half. Same f2bf chain as k_prod.
//   - granule 8 (all 16 feature chunks) and the coord chunk 16 computed
//     once in prologue into static LDS (g8, c16) -> uniform main loop.
//   - staging loads consumed in-wave before the barrier -> plain
//     __syncthreads() is free (no counted-vmcnt needed). v5 aR/aN dbuf.
//   Kills 82 MB HBM round-trip (Pf write+read) + one launch.

typedef __attribute__((ext_vector_type(8))) short short8;
typedef __attribute__((ext_vector_type(4))) short short4v;
typedef __attribute__((ext_vector_type(4))) float f32x4;

__device__ __forceinline__ float bf2f(unsigned short h) {
  return __uint_as_float(((unsigned int)h) << 16);
}
__device__ __forceinline__ unsigned short f2bf(float f) {
  unsigned int u = __float_as_uint(f);
  u += 0x7FFFu + ((u >> 16) & 1u);
  return (unsigned short)(u >> 16);
}

// 8 bf16 products -> bf16 (identical numerics to old k_prod)
__device__ __forceinline__ short8 prod8(short8 cl, short8 cr) {
  short8 p;
#pragma unroll
  for (int e = 0; e < 8; ++e)
    p[e] = (short)f2bf(bf2f((unsigned short)cl[e]) * bf2f((unsigned short)cr[e]));
  return p;
}

// ---------------------------------------------------------------------------
// K_prep: bid<2304: mm -> bf16 (mmb).
//         bid>=2304: weights -> MFMA fragment order:
//           WS  (A for k_pairwise): kc<16 from Wfout[k,d] (k=kc*32+q*8+e),
//                kc==16: Mc[kk,d] = sum_h Wcl[a,h]Wcr[b,h]Wcout[h,d] computed
//                inline (kk=qv*8+e<16, a=kk>>2, b=kk&3; qv>=2 -> 0 pad)
//           WS2 (B for k_proj_feat): (Wfl|Wfr)^T fragments.
__global__ __launch_bounds__(256) void k_prep(
    const float* __restrict__ mm, const float* __restrict__ Wfout,
    const float* __restrict__ Wcl, const float* __restrict__ Wcr,
    const float* __restrict__ Wcout, const float* __restrict__ Wfl,
    const float* __restrict__ Wfr, unsigned short* __restrict__ mmb,
    unsigned short* __restrict__ WS, unsigned short* __restrict__ WS2) {
  const int bid = blockIdx.x;
  if (bid < 2304) {
    int idx = bid * 256 + threadIdx.x;  // 0 .. 1152*512-1
    int row = idx >> 9, h = idx & 511;
    float4 m4 = *(const float4*)(mm + (size_t)row * 2048 + h * 4);
    short4v o;
    o[0] = (short)f2bf(m4.x); o[1] = (short)f2bf(m4.y);
    o[2] = (short)f2bf(m4.z); o[3] = (short)f2bf(m4.w);
    *(short4v*)(mmb + (size_t)row * 2048 + h * 4) = o;
  } else {
    int gi = (bid - 2304) * 256 + threadIdx.x;  // 0..401407
    if (gi < 139264) {
      // WS granule gi = ((g2*17+kc)*4+q)*16+n ; elem e: d=g2*16+n, k=kc*32+q*8+e
      int n = gi & 15, qv = (gi >> 4) & 3, rest = gi >> 6;
      int kc = rest % 17, g2 = rest / 17;
      int d = g2 * 16 + n;
      short8 o;
      if (kc < 16) {
        int kbase = kc * 32 + qv * 8;
        const float* src = Wfout + (size_t)kbase * 2048 + d;
#pragma unroll
        for (int e = 0; e < 8; ++e) o[e] = (short)f2bf(src[(size_t)e * 2048]);
      } else if (qv < 2) {
        // inline Mc: o[e] = sum_h Wcl[qv*2+(e>>2),h]*Wcr[e&3,h]*Wcout[h,d]
        float acc[8];
#pragma unroll
        for (int e = 0; e < 8; ++e) acc[e] = 0.f;
#pragma unroll 4
        for (int h = 0; h < 512; ++h) {
          float wo = Wcout[(size_t)h * 2048 + d];
          float c0 = Wcl[(qv * 2 + 0) * 512 + h] * wo;
          float c1 = Wcl[(qv * 2 + 1) * 512 + h] * wo;
          float r0 = Wcr[h], r1 = Wcr[512 + h];
          float r2 = Wcr[1024 + h], r3 = Wcr[1536 + h];
          acc[0] += c0 * r0; acc[1] += c0 * r1;
          acc[2] += c0 * r2; acc[3] += c0 * r3;
          acc[4] += c1 * r0; acc[5] += c1 * r1;
          acc[6] += c1 * r2; acc[7] += c1 * r3;
        }
#pragma unroll
        for (int e = 0; e < 8; ++e) o[e] = (short)f2bf(acc[e]);
      } else {
#pragma unroll
        for (int e = 0; e < 8; ++e) o[e] = 0;
      }
      *(short8*)(WS + (size_t)gi * 8) = o;
    } else {
      // WS2 granule gj = ((cg*64+kc)*4+q)*16+n ; elem e: col=cg*16+n, dd=kc*32+q*8+e
      int gj = gi - 139264;
      int n = gj & 15, qv = (gj >> 4) & 3, kc = (gj >> 6) & 63, cg = gj >> 12;
      int col = cg * 16 + n;
      int dbase = kc * 32 + qv * 8;
      const float* src = (col < 512) ? (Wfl + (size_t)dbase * 512 + col)
                                     : (Wfr + (size_t)dbase * 512 + (col - 512));
      short8 o;
#pragma unroll
      for (int e = 0; e < 8; ++e) o[e] = (short)f2bf(src[(size_t)e * 512]);
      *(short8*)(WS2 + (size_t)gj * 8) = o;
    }
  }
}

// ---------------------------------------------------------------------------
// K3: feature projection O[row,col] = sum_dd mmb[row,dd]*Wlr[dd,col]
//  col<512 -> Fl[row][col] ; else -> Fr[row][col-512]   (bf16 out)
__global__ __launch_bounds__(256) void k_proj_feat(
    const unsigned short* __restrict__ mmb, const unsigned short* __restrict__ WS2,
    unsigned short* __restrict__ Fl, unsigned short* __restrict__ Fr) {
  const int tid = threadIdx.x;
  const int lane = tid & 63, w = tid >> 6;
  const int n = lane & 15, q = lane >> 4;
  const int m0 = blockIdx.y * 16;
  const int cg = blockIdx.x * 4 + w;  // 0..63
  const int c0 = cg * 16;

  f32x4 acc = {0.f, 0.f, 0.f, 0.f};
#pragma unroll 4
  for (int kc = 0; kc < 64; ++kc) {
    short8 a = *(const short8*)(mmb + (size_t)(m0 + n) * 2048 + kc * 32 + q * 8);
    short8 b = *(const short8*)(WS2 + (size_t)(cg * 64 + kc) * 512 + lane * 8);
    acc = __builtin_amdgcn_mfma_f32_16x16x32_bf16(a, b, acc, 0, 0, 0);
  }
#pragma unroll
  for (int e = 0; e < 4; ++e) {
    int row = m0 + q * 4 + e;
    int col = c0 + n;
    unsigned short v = f2bf(acc[e]);
    if (col < 512) Fl[(size_t)row * 512 + col] = v;
    else           Fr[(size_t)row * 512 + (col - 512)] = v;
  }
}

// ---------------------------------------------------------------------------
// K4 (fused): streaming GEMM + in-loop pair products + max-over-j + residual.
// 512 thr / 8 waves, r=2, XCD-clustered grid (v5 map). NK=17 chunks.
// LDS: ring[2][8*512] dbuf (granules t=0..7) + g8[16*512] (granule 8, all
// feature chunks; prologue) + c16[9*512] (coord chunk 16; prologue) = 41 KB.
// Body c (0..14): load cl/cr(c+1) + A(c+1); MFMA(c) from ring[c&1]+g8[c];
// products(c+1) -> ring[(c+1)&1]; __syncthreads (vmcnt(0) only sees ~450cy-old
// aN loads -> free). Then chunk 15 (ring[1], no barrier), chunk 16 (c16).
// Granule t=w: g=g0+(w>>1), j=(w&1)*16+n, k=kc*32+q*8+e; same layout as the
// deleted k_prod, so MFMA consumption is unchanged.
__global__ __launch_bounds__(512, 4) void k_pairwise(
    const unsigned short* __restrict__ Fl, const unsigned short* __restrict__ Fr,
    const float* __restrict__ coords, const unsigned short* __restrict__ WS,
    const float* __restrict__ mm, float* __restrict__ out) {
  __shared__ __align__(16) unsigned short ring[2][8 * 512];  // 16 KB
  __shared__ __align__(16) unsigned short g8[16 * 512];      // 16 KB
  __shared__ __align__(16) unsigned short c16[9 * 512];      // 9 KB

  const int tid = threadIdx.x;
  const int lane = tid & 63, w = tid >> 6;  // w 0..7
  const int n = lane & 15, q = lane >> 4;
  const int bx = blockIdx.x;
  const int x = bx & 7;       // XCD id under round-robin dispatch
  const int m = bx >> 3;      // 0..287 per-XCD slot
  const int dt = m & 7;       // d-tile: siblings consecutive on the XCD
  const int qg = x * 36 + (m >> 3);  // qg clustered per XCD (bijective)
  const int g0 = qg * 4;
  const int b36 = (qg / 9) * 36;

  f32x4 acc[9][2];
#pragma unroll
  for (int t = 0; t < 9; ++t)
#pragma unroll
    for (int r = 0; r < 2; ++r) acc[t][r] = (f32x4){0.f, 0.f, 0.f, 0.f};

  // A granule (r, kc): WS + ((dt*16 + w*2 + r)*17 + kc)*512 + lane*8
  const unsigned short* Abase = WS + ((size_t)(dt * 16 + w * 2) * 17) * 512 + lane * 8;

  // primary product slot (granule t=w): g=g0+(w>>1), j=(w&1)*16+n
  const int gp = g0 + (w >> 1);
  const int jp = (w & 1) * 16 + n;
  const unsigned short* FlP = Fl + (size_t)gp * 512 + q * 8;         // +kc*32
  const unsigned short* FrP = Fr + (size_t)(b36 + jp) * 512 + q * 8; // +kc*32
  // shared-granule slot (t=8): g=g0+(n>>2), j=32+(n&3)
  const int gs = g0 + (n >> 2);
  const int js = 32 + (n & 3);

  short8 aR[2], aN[2];

  // ---- prologue ----
  // chunk 0 products -> ring[0]
  {
    short8 cl = *(const short8*)(FlP);
    short8 cr = *(const short8*)(FrP);
    *(short8*)(&ring[0][w * 512 + lane * 8]) = prod8(cl, cr);
  }
  // g8: granule t=8 for feature chunks s=w and s=w+8
#pragma unroll
  for (int si = 0; si < 2; ++si) {
    int s = w + si * 8;
    short8 cl = *(const short8*)(Fl + (size_t)gs * 512 + s * 32 + q * 8);
    short8 cr = *(const short8*)(Fr + (size_t)(b36 + js) * 512 + s * 32 + q * 8);
    *(short8*)(&g8[s * 512 + lane * 8]) = prod8(cl, cr);
  }
  // c16: coord-chunk granules. t=w uses (gp,jp); wave 0 also does t=8 (gs,js).
  {
    short8 cp;
    if (q < 2) {
      float4 ci = *(const float4*)(coords + (size_t)gp * 4);
      float4 cj = *(const float4*)(coords + (size_t)(b36 + jp) * 4);
#pragma unroll
      for (int e = 0; e < 8; ++e) {
        int a = q * 2 + (e >> 2);
        float ca = (a == 0) ? ci.x : (a == 1) ? ci.y : (a == 2) ? ci.z : ci.w;
        float cb = ((e & 3) == 0) ? cj.x : ((e & 3) == 1) ? cj.y
                 : ((e & 3) == 2) ? cj.z : cj.w;
        cp[e] = (short)f2bf(ca * cb);
      }
    } else {
#pragma unroll
      for (int e = 0; e < 8; ++e) cp[e] = 0;
    }
    *(short8*)(&c16[w * 512 + lane * 8]) = cp;
    if (w == 0) {
      short8 cs;
      if (q < 2) {
        float4 ci = *(const float4*)(coords + (size_t)gs * 4);
        float4 cj = *(const float4*)(coords + (size_t)(b36 + js) * 4);
#pragma unroll
        for (int e = 0; e < 8; ++e) {
          int a = q * 2 + (e >> 2);
          float ca = (a == 0) ? ci.x : (a == 1) ? ci.y : (a == 2) ? ci.z : ci.w;
          float cb = ((e & 3) == 0) ? cj.x : ((e & 3) == 1) ? cj.y
                   : ((e & 3) == 2) ? cj.z : cj.w;
          cs[e] = (short)f2bf(ca * cb);
        }
      } else {
#pragma unroll
        for (int e = 0; e < 8; ++e) cs[e] = 0;
      }
      *(short8*)(&c16[8 * 512 + lane * 8]) = cs;
    }
  }
  aR[0] = *(const short8*)(Abase);
  aR[1] = *(const short8*)(Abase + 17 * 512);
  __syncthreads();

  // ---- main loop: chunks 0..14, staging products for c+1 ----
#pragma unroll 2
  for (int c = 0; c < 15; ++c) {
    const int buf = c & 1;
    // issue-early: product operands for chunk c+1 + A(c+1)
    short8 cl = *(const short8*)(FlP + (c + 1) * 32);
    short8 cr = *(const short8*)(FrP + (c + 1) * 32);
    aN[0] = *(const short8*)(Abase + (size_t)(c + 1) * 512);
    aN[1] = *(const short8*)(Abase + (size_t)(17 + c + 1) * 512);

    // MFMA phase: chunk c
    short8 bb[9];
#pragma unroll
    for (int t = 0; t < 8; ++t)
      bb[t] = *(const short8*)(&ring[buf][t * 512 + lane * 8]);
    bb[8] = *(const short8*)(&g8[c * 512 + lane * 8]);
#pragma unroll
    for (int t = 0; t < 9; ++t) {
      acc[t][0] = __builtin_amdgcn_mfma_f32_16x16x32_bf16(aR[0], bb[t], acc[t][0], 0, 0, 0);
      acc[t][1] = __builtin_amdgcn_mfma_f32_16x16x32_bf16(aR[1], bb[t], acc[t][1], 0, 0, 0);
    }
    // consume-late: products for chunk c+1 into the other buffer
    *(short8*)(&ring[buf ^ 1][w * 512 + lane * 8]) = prod8(cl, cr);
    __syncthreads();
    aR[0] = aN[0];
    aR[1] = aN[1];
  }

  // chunk 15 (ring[1], g8[15]); load A(16); no staging, no barrier after
  {
    aN[0] = *(const short8*)(Abase + (size_t)16 * 512);
    aN[1] = *(const short8*)(Abase + (size_t)(17 + 16) * 512);
    short8 bb[9];
#pragma unroll
    for (int t = 0; t < 8; ++t)
      bb[t] = *(const short8*)(&ring[1][t * 512 + lane * 8]);
    bb[8] = *(const short8*)(&g8[15 * 512 + lane * 8]);
#pragma unroll
    for (int t = 0; t < 9; ++t) {
      acc[t][0] = __builtin_amdgcn_mfma_f32_16x16x32_bf16(aR[0], bb[t], acc[t][0], 0, 0, 0);
      acc[t][1] = __builtin_amdgcn_mfma_f32_16x16x32_bf16(aR[1], bb[t], acc[t][1], 0, 0, 0);
    }
  }
  // chunk 16 (coord, c16 static)
  {
    short8 bb[9];
#pragma unroll
    for (int t = 0; t < 9; ++t)
      bb[t] = *(const short8*)(&c16[t * 512 + lane * 8]);
#pragma unroll
    for (int t = 0; t < 9; ++t) {
      acc[t][0] = __builtin_amdgcn_mfma_f32_16x16x32_bf16(aN[0], bb[t], acc[t][0], 0, 0, 0);
      acc[t][1] = __builtin_amdgcn_mfma_f32_16x16x32_bf16(aN[1], bb[t], acc[t][1], 0, 0, 0);
    }
  }

  // epilogue: per (ii,r,e): max over full tiles 2ii,2ii+1 (j=n, 16+n) and the
  // shared tile's lanes with n>>2==ii (j=32+(n&3)); xor-reduce over 16 n-lanes.
#pragma unroll
  for (int r = 0; r < 2; ++r) {
#pragma unroll
    for (int e = 0; e < 4; ++e) {
      float vs = acc[8][r][e];
#pragma unroll
      for (int ii = 0; ii < 4; ++ii) {
        float v = fmaxf(acc[ii * 2][r][e], acc[ii * 2 + 1][r][e]);
        v = fmaxf(v, ((n >> 2) == ii) ? vs : -1e30f);
#pragma unroll
        for (int s = 1; s < 16; s <<= 1) v = fmaxf(v, __shfl_xor(v, s, 64));
        if (n == 0) {
          int d = dt * 256 + w * 32 + r * 16 + q * 4 + e;
          size_t o = (size_t)(g0 + ii) * 2048 + d;
          out[o] = v + mm[o];
        }
      }
    }
  }
}

// ---------------------------------------------------------------------------
extern "C" void kernel_launch(void* const* d_in, const int* in_sizes, int n_in,
                              void* d_out, int out_size, void* d_ws, size_t ws_size,
                              hipStream_t stream) {
  const float* mm     = (const float*)d_in[0];
  const float* coords = (const float*)d_in[1];
  const float* Wcl    = (const float*)d_in[2];
  const float* Wcr    = (const float*)d_in[3];
  const float* Wcout  = (const float*)d_in[4];
  const float* Wfl    = (const float*)d_in[5];
  const float* Wfr    = (const float*)d_in[6];
  const float* Wfout  = (const float*)d_in[7];
  float* out = (float*)d_out;

  // workspace ~14 MB (Pf eliminated)
  unsigned short* Fl  = (unsigned short*)d_ws;              // [1152][512] bf16
  unsigned short* Fr  = Fl + (size_t)1152 * 512;            // [1152][512] bf16
  unsigned short* WS  = Fr + (size_t)1152 * 512;            // 139264 gran x 8
  unsigned short* WS2 = WS + (size_t)139264 * 8;            // 262144 gran x 8
  unsigned short* mmb = WS2 + (size_t)262144 * 8;           // [1152][2048] bf16

  k_prep<<<2304 + 1568, 256, 0, stream>>>(mm, Wfout, Wcl, Wcr, Wcout,
                                          Wfl, Wfr, mmb, WS, WS2);
  k_proj_feat<<<dim3(16, 72), 256, 0, stream>>>(mmb, WS2, Fl, Fr);
  k_pairwise<<<2304, 512, 0, stream>>>(Fl, Fr, coords, WS, mm, out);
}